// Round 18
// baseline (87.369 us; speedup 1.0000x reference)
//
#include <hip/hip_runtime.h>
#include <math.h>

#define N_SEQ 2048
#define DIMC 512
#define INNER 256
#define C2F (0.17677669529663687f * 1.4426950408889634f)  // scale * log2(e)
#define C2F2 (C2F * C2F)

typedef short bf16x8 __attribute__((ext_vector_type(8)));
typedef float f32x4 __attribute__((ext_vector_type(4)));

// ws layout (bytes):
//  ushort units: Q [0,2M): [bh][g:4][n:2048][8]   K [2M,4M): same
//                Vt [4M,6M): [bh][c:256][d:32][8]
//  k2*C2F2 @12.25MB
//  att16 bf16 @13MB..17MB [b][n][256]
//  xt16 @21MB..29MB   wq16 @29MB..29.75MB   wo16 @30MB..30.25MB

static __device__ __forceinline__ ushort f2bf(float f) {
    uint x = __float_as_uint(f);
    x += 0x7fff + ((x >> 16) & 1);
    return (ushort)(x >> 16);
}
static __device__ __forceinline__ float bf2f(ushort u) {
    return __uint_as_float(((uint)u) << 16);
}
static __device__ __forceinline__ float fast_exp2_neg(float x) {  // exp2(-x)
    float r; asm("v_exp_f32 %0, -%1" : "=v"(r) : "v"(x)); return r;
}
static __device__ __forceinline__ float fast_sqrt(float x) {
    float r; asm("v_sqrt_f32 %0, %1" : "=v"(r) : "v"(x)); return r;
}
// async global->LDS DMA: dest = uniform base + lane*size (HW rule)
static __device__ __forceinline__ void gload16(const void* g, void* l) {
    __builtin_amdgcn_global_load_lds(
        (const __attribute__((address_space(1))) void*)g,
        (__attribute__((address_space(3))) void*)l, 16, 0, 0);
}
static __device__ __forceinline__ void gload4(const void* g, void* l) {
    __builtin_amdgcn_global_load_lds(
        (const __attribute__((address_space(1))) void*)g,
        (__attribute__((address_space(3))) void*)l, 4, 0, 0);
}

// ---------------------------------------------------------------------------
// Fused prep: x transpose/convert (1024 blocks) + weight cvts (512 blocks)
// ---------------------------------------------------------------------------
__global__ void prep_kernel(const float* __restrict__ x,
                            const float* __restrict__ wq,
                            const float* __restrict__ wo,
                            ushort* __restrict__ xt,
                            ushort* __restrict__ wq16,
                            ushort* __restrict__ wo16) {
    __shared__ __align__(16) ushort T[64][72];
    const int bid = blockIdx.x;
    const int t = threadIdx.x;
    if (bid < 1024) {
        const int n0 = (bid & 31) * 64;
        const int c0 = ((bid >> 5) & 7) * 64;
        const int b = bid >> 8;
        const int cl = t >> 4;
        const int n4 = (t & 15) * 4;
        const float* xb = x + ((size_t)b * DIMC + c0) * N_SEQ + n0;
#pragma unroll
        for (int cc = 0; cc < 4; ++cc) {
            const int c = cl + cc * 16;
            float4 v = *(const float4*)(xb + (size_t)c * N_SEQ + n4);
            T[n4 + 0][c] = f2bf(v.x);
            T[n4 + 1][c] = f2bf(v.y);
            T[n4 + 2][c] = f2bf(v.z);
            T[n4 + 3][c] = f2bf(v.w);
        }
        __syncthreads();
        const int nl = t >> 2;
        const int c16 = (t & 3) * 16;
        uint4 v0 = *(const uint4*)&T[nl][c16];
        uint4 v1 = *(const uint4*)&T[nl][c16 + 8];
        ushort* dst = xt + ((size_t)b * N_SEQ + n0 + nl) * DIMC + c0 + c16;
        *(uint4*)dst = v0;
        *(uint4*)(dst + 8) = v1;
    } else if (bid < 1408) {
        int i = ((bid - 1024) * 256 + t) * 4;
        float4 v = *(const float4*)(wq + i);
        ushort4 p;
        p.x = f2bf(v.x); p.y = f2bf(v.y); p.z = f2bf(v.z); p.w = f2bf(v.w);
        *(ushort4*)(wq16 + i) = p;
    } else {
        int i = ((bid - 1408) * 256 + t) * 4;
        float4 v = *(const float4*)(wo + i);
        ushort4 p;
        p.x = f2bf(v.x); p.y = f2bf(v.y); p.z = f2bf(v.z); p.w = f2bf(v.w);
        *(ushort4*)(wo16 + i) = p;
    }
}

// ---------------------------------------------------------------------------
// QKV projection, bf16 MFMA. 64x64 tile, BK=32, 4 waves.
// ---------------------------------------------------------------------------
__global__ __launch_bounds__(256) void qkv_mfma(const ushort* __restrict__ xt,
        const ushort* __restrict__ w16, ushort* __restrict__ ws16) {
    __shared__ __align__(16) ushort Wls[4 * 520];
    __shared__ __align__(16) ushort Xls[4 * 520];
    const int b = blockIdx.z;
    const int o0 = blockIdx.y * 64;
    const int n0 = blockIdx.x * 64;
    const int t = threadIdx.x;
    const int l = t & 63, w = t >> 6;
    const int q15 = l & 15, g = l >> 4;
    f32x4 acc[4];
#pragma unroll
    for (int nn = 0; nn < 4; ++nn) acc[nn] = (f32x4){0.f, 0.f, 0.f, 0.f};
    const int srow = t >> 2, sg = t & 3;
    const ushort* wsrc = w16 + (size_t)(o0 + srow) * DIMC + sg * 8;
    const ushort* xsrc = xt + ((size_t)b * N_SEQ + n0 + srow) * DIMC + sg * 8;
    uint4 wreg = *(const uint4*)wsrc;
    uint4 xreg = *(const uint4*)xsrc;
    for (int k0 = 0; k0 < DIMC; k0 += 32) {
        __builtin_amdgcn_s_barrier();
        __builtin_amdgcn_sched_barrier(0);
        *(uint4*)(Wls + sg * 520 + srow * 8) = wreg;
        *(uint4*)(Xls + sg * 520 + srow * 8) = xreg;
        if (k0 + 32 < DIMC) {
            wreg = *(const uint4*)(wsrc + k0 + 32);
            xreg = *(const uint4*)(xsrc + k0 + 32);
        }
        asm volatile("s_waitcnt lgkmcnt(0)" ::: "memory");
        __builtin_amdgcn_s_barrier();
        __builtin_amdgcn_sched_barrier(0);
        bf16x8 af = *(const bf16x8*)(Wls + g * 520 + (16 * w + q15) * 8);
        __builtin_amdgcn_s_setprio(1);
#pragma unroll
        for (int nn = 0; nn < 4; ++nn) {
            bf16x8 bfr = *(const bf16x8*)(Xls + g * 520 + (16 * nn + q15) * 8);
            acc[nn] = __builtin_amdgcn_mfma_f32_16x16x32_bf16(af, bfr, acc[nn], 0, 0, 0);
        }
        __builtin_amdgcn_s_setprio(0);
    }
    const int oatom = o0 + 16 * w;
    const int t_idx = oatom >> 8;
    const int h = (oatom >> 5) & 7;
    const int bh = b * 8 + h;
    const int d0 = (oatom & 31) + 4 * g;
    if (t_idx < 2) {
        ushort* dst = ws16 + (size_t)t_idx * 2097152 + (size_t)bh * 65536
                      + (size_t)(d0 >> 3) * 16384 + (d0 & 7);
#pragma unroll
        for (int nn = 0; nn < 4; ++nn) {
            const int n_ = n0 + 16 * nn + q15;
            ushort4 p;
            p.x = f2bf(acc[nn][0]); p.y = f2bf(acc[nn][1]);
            p.z = f2bf(acc[nn][2]); p.w = f2bf(acc[nn][3]);
            *(ushort4*)(dst + (size_t)n_ * 8) = p;
        }
    } else {
        ushort* dst = ws16 + (size_t)4194304 + (size_t)bh * 65536;
#pragma unroll
        for (int nn = 0; nn < 4; ++nn) {
            const int n_ = n0 + 16 * nn + q15;
            ushort* dd = dst + (size_t)(n_ >> 3) * 256 + (n_ & 7);
            dd[(d0 + 0) * 8] = f2bf(acc[nn][0]);
            dd[(d0 + 1) * 8] = f2bf(acc[nn][1]);
            dd[(d0 + 2) * 8] = f2bf(acc[nn][2]);
            dd[(d0 + 3) * 8] = f2bf(acc[nn][3]);
        }
    }
}

// ---------------------------------------------------------------------------
// k2 from bf16 values, prescaled by C2F^2
// ---------------------------------------------------------------------------
__global__ void sq_kernel(const ushort* __restrict__ ws16, float* __restrict__ k2) {
    const int idx = blockIdx.x * 256 + threadIdx.x;
    const int bh = idx >> 11, n = idx & 2047;
    const ushort* base = ws16 + 2097152 + (size_t)bh * 65536 + (size_t)n * 8;
    float s = 0.f;
#pragma unroll
    for (int g = 0; g < 4; ++g) {
        uint4 v = *(const uint4*)(base + (size_t)g * 16384);
        uint a[4] = {v.x, v.y, v.z, v.w};
#pragma unroll
        for (int e = 0; e < 4; ++e) {
            float lo = bf2f((ushort)(a[e] & 0xffff));
            float hi = bf2f((ushort)(a[e] >> 16));
            s += lo * lo + hi * hi;
        }
    }
    k2[idx] = s * (float)C2F2;
}

// ---------------------------------------------------------------------------
// Flash L2 attention — 3-buffer ring + CROSS-TILE COMPUTE PIPELINE:
// st(t) (QK^T results) are computed during tile t-1, so scores(t) start
// immediately after the barrier with zero MFMA wait; QK^T(t+1) MFMAs issue
// between scores-pack(t) and PV(t), filling the Pls write->read lgkm gap.
// Ring invariant: at tile t (after vmcnt(0)+barrier) bufs t%3 and (t+1)%3
// are both valid (STAGE(t+1) was issued a full tile ago; vmcnt(0) there is
// ~free); STAGE(t+2) overwrites buf (t-1)%3, last read before this tile's
// barrier -> single barrier per tile remains correct. st carries 16 VGPR
// across iterations; producer is LDS-read (barrier-fenced) so the allocator
// cannot sink it to use (unlike R8/R10/R11 global-load pipelines).
// m=0 fixed softmax shift (exact). LDS 34.6KB -> 4 blocks/CU.
// ---------------------------------------------------------------------------
__global__ __launch_bounds__(256, 4) void attn_kernel(
        const ushort* __restrict__ ws16, const float* __restrict__ k2g,
        ushort* __restrict__ att16) {
    __shared__ __align__(16) ushort Kls[3 * 2048];   // [buf][g:4][j:64][8]
    __shared__ __align__(16) ushort Vls[3 * 2048];   // [buf][c:8][d:32][8]
    __shared__ __align__(16) float k2ls[3 * 64];     // [buf][64]
    __shared__ __align__(16) ushort Pls[4][16][72];  // per-wave P, 144B rows
    const int bid = blockIdx.x;                   // 1024 blocks
    const int sw = (bid & 7) * 128 + (bid >> 3);  // bijective XCD swizzle
    const int q0 = (sw & 31) * 64;
    const int bh = sw >> 5;
    const int b = bh >> 3, h = bh & 7;
    const int tid = threadIdx.x;
    const int l = tid & 63;
    const int w = tid >> 6;
    const int q15 = l & 15;
    const int g = l >> 4;
    const int qrow = q0 + 16 * w + q15;

    const ushort* Qbh = ws16 + (size_t)bh * 65536;
    const ushort* Kbh = ws16 + 2097152 + (size_t)bh * 65536;
    const ushort* Vbh = ws16 + 4194304 + (size_t)bh * 65536;
    const float* k2bh = k2g + (size_t)bh * 2048;

#define STAGE(T, BUF)                                                         \
    {                                                                         \
        const int j0s = (T) * 64;                                             \
        gload16(Kbh + (size_t)w * 16384 + (size_t)(j0s + l) * 8,              \
                Kls + (BUF) * 2048 + w * 512);                                \
        gload16(Vbh + (size_t)j0s * 32 + (size_t)w * 512 + (size_t)l * 8,     \
                Vls + (BUF) * 2048 + w * 512);                                \
        gload4(k2bh + j0s + l, k2ls + (BUF) * 64);                            \
    }

    // prologue: depth-2 prefetch
    STAGE(0, 0)
    STAGE(1, 1)

    const bf16x8 qf = *(const bf16x8*)(Qbh + (size_t)g * 16384 + (size_t)qrow * 8);
    float q2l = 0.f;
#pragma unroll
    for (int e = 0; e < 8; ++e) {
        float qe = bf2f((ushort)qf[e]);
        q2l = fmaf(qe, qe, q2l);
    }
    q2l += __shfl_xor(q2l, 16);
    q2l += __shfl_xor(q2l, 32);
    const float q2v = q2l * (float)C2F2;

    ushort* plane = &Pls[w][q15][0];
    f32x4 accO[2];
    accO[0] = (f32x4){0.f, 0.f, 0.f, 0.f};
    accO[1] = (f32x4){0.f, 0.f, 0.f, 0.f};
    float lsm = 0.f;
    const f32x4 zz = (f32x4){0.f, 0.f, 0.f, 0.f};
    f32x4 st[4];   // QK^T of the *current* tile, computed one tile early

    // wait for STAGE(0) only (3 newest = STAGE(1) may remain in flight)
    asm volatile("s_waitcnt vmcnt(3)" ::: "memory");
    __builtin_amdgcn_s_barrier();
    __builtin_amdgcn_sched_barrier(0);
    {   // QK^T(0) from buf 0
        bf16x8 kf[4];
#pragma unroll
        for (int k = 0; k < 4; ++k)
            kf[k] = *(const bf16x8*)(Kls + g * 512 + (16 * k + q15) * 8);
#pragma unroll
        for (int k = 0; k < 4; ++k)
            st[k] = __builtin_amdgcn_mfma_f32_16x16x32_bf16(kf[k], qf, zz, 0, 0, 0);
    }

    int bc = 0;           // t % 3
    int bn = 1;           // (t+1) % 3
    int sb = 2;           // (t+2) % 3
#pragma unroll 1
    for (int t = 0; t < 32; ++t) {
        // drain all DMAs (newest batch issued a full tile ago -> ~free),
        // making bufs bc AND bn valid behind one barrier.
        asm volatile("s_waitcnt vmcnt(0)" ::: "memory");
        __builtin_amdgcn_s_barrier();
        __builtin_amdgcn_sched_barrier(0);

        // ---- scores(t): st ready since last tile; no MFMA wait ----
        const float* k2P = k2ls + bc * 64;
        float lt = 0.f;
#pragma unroll
        for (int k = 0; k < 4; ++k) {
            float4 kk = *(const float4*)(k2P + 16 * k + 4 * g);
            float ka[4] = {kk.x, kk.y, kk.z, kk.w};
            float pr[4];
#pragma unroll
            for (int r = 0; r < 4; ++r) {
                float a = q2v + ka[r];
                float d2 = fmaf(-2.f * (float)C2F2, st[k][r], a);
                pr[r] = fast_exp2_neg(fast_sqrt(fmaxf(d2, 1e-12f)));
            }
            lt += (pr[0] + pr[1]) + (pr[2] + pr[3]);
            uint pk0, pk1;
            asm("v_cvt_pk_bf16_f32 %0, %1, %2" : "=v"(pk0) : "v"(pr[0]), "v"(pr[1]));
            asm("v_cvt_pk_bf16_f32 %0, %1, %2" : "=v"(pk1) : "v"(pr[2]), "v"(pr[3]));
            uint2 pv; pv.x = pk0; pv.y = pk1;
            *(uint2*)(plane + 16 * k + 4 * g) = pv;
        }
        lsm += lt;

        // ---- QK^T(t+1) from buf bn: fills the Pls write->read gap ----
        if (t + 1 < 32) {
            bf16x8 kf[4];
#pragma unroll
            for (int k = 0; k < 4; ++k)
                kf[k] = *(const bf16x8*)(Kls + bn * 2048 + g * 512
                                         + (16 * k + q15) * 8);
            __builtin_amdgcn_s_setprio(1);
#pragma unroll
            for (int k = 0; k < 4; ++k)
                st[k] = __builtin_amdgcn_mfma_f32_16x16x32_bf16(kf[k], qf, zz, 0, 0, 0);
            __builtin_amdgcn_s_setprio(0);
        }

        // ---- stage t+2 into buf sb (== buf (t-1)%3, dead since barrier) ----
        if (t + 2 < 32) {
            STAGE(t + 2, sb)
        }

        // ---- PV(t) ----
        const ushort* VlsP = Vls + bc * 2048;
        __builtin_amdgcn_s_setprio(1);
#pragma unroll
        for (int jc = 0; jc < 2; ++jc) {
            bf16x8 pf = *(const bf16x8*)(plane + 32 * jc + 8 * g);
#pragma unroll
            for (int dh = 0; dh < 2; ++dh) {
                bf16x8 vf = *(const bf16x8*)(VlsP + (4 * jc + g) * 256
                                             + (16 * dh + q15) * 8);
                accO[dh] = __builtin_amdgcn_mfma_f32_16x16x32_bf16(vf, pf, accO[dh], 0, 0, 0);
            }
        }
        __builtin_amdgcn_s_setprio(0);

        bc = (bc == 2) ? 0 : bc + 1;
        bn = (bn == 2) ? 0 : bn + 1;
        sb = (sb == 2) ? 0 : sb + 1;
    }
#undef STAGE

    lsm += __shfl_xor(lsm, 16);
    lsm += __shfl_xor(lsm, 32);
    const float invl = 1.f / lsm;
    ushort* dst = att16 + ((size_t)(b * N_SEQ + qrow)) * INNER + h * 32 + 4 * g;
#pragma unroll
    for (int d = 0; d < 2; ++d) {
        ushort4 o;
        o.x = f2bf(accO[d][0] * invl); o.y = f2bf(accO[d][1] * invl);
        o.z = f2bf(accO[d][2] * invl); o.w = f2bf(accO[d][3] * invl);
        *(ushort4*)(dst + d * 16) = o;
    }
}

// ---------------------------------------------------------------------------
// Output projection, bf16 MFMA
// ---------------------------------------------------------------------------
__global__ __launch_bounds__(256) void out_mfma(const ushort* __restrict__ att16,
        const ushort* __restrict__ wo16, const float* __restrict__ bias,
        float* __restrict__ out) {
    __shared__ __align__(16) ushort Wls[4 * 520];
    __shared__ __align__(16) ushort Als[4 * 520];
    const int b = blockIdx.z;
    const int o0 = blockIdx.y * 64;
    const int n0 = blockIdx.x * 64;
    const int t = threadIdx.x;
    const int l = t & 63, w = t >> 6;
    const int q15 = l & 15, g = l >> 4;
    f32x4 acc[4];
#pragma unroll
    for (int nn = 0; nn < 4; ++nn) acc[nn] = (f32x4){0.f, 0.f, 0.f, 0.f};
    const int srow = t >> 2, sg = t & 3;
    const ushort* wsrc = wo16 + (size_t)(o0 + srow) * INNER + sg * 8;
    const ushort* asrc = att16 + ((size_t)b * N_SEQ + n0 + srow) * INNER + sg * 8;
    uint4 wreg = *(const uint4*)wsrc;
    uint4 areg = *(const uint4*)asrc;
    for (int k0 = 0; k0 < INNER; k0 += 32) {
        __builtin_amdgcn_s_barrier();
        __builtin_amdgcn_sched_barrier(0);
        *(uint4*)(Wls + sg * 520 + srow * 8) = wreg;
        *(uint4*)(Als + sg * 520 + srow * 8) = areg;
        if (k0 + 32 < INNER) {
            wreg = *(const uint4*)(wsrc + k0 + 32);
            areg = *(const uint4*)(asrc + k0 + 32);
        }
        asm volatile("s_waitcnt lgkmcnt(0)" ::: "memory");
        __builtin_amdgcn_s_barrier();
        __builtin_amdgcn_sched_barrier(0);
        bf16x8 af = *(const bf16x8*)(Wls + g * 520 + (16 * w + q15) * 8);
        __builtin_amdgcn_s_setprio(1);
#pragma unroll
        for (int nn = 0; nn < 4; ++nn) {
            bf16x8 bfr = *(const bf16x8*)(Als + g * 520 + (16 * nn + q15) * 8);
            acc[nn] = __builtin_amdgcn_mfma_f32_16x16x32_bf16(af, bfr, acc[nn], 0, 0, 0);
        }
        __builtin_amdgcn_s_setprio(0);
    }
    const int obase = o0 + 16 * w + 4 * g;
    float4 bi = *(const float4*)(bias + obase);
    float* ob = out + ((size_t)b * DIMC + obase) * N_SEQ;
#pragma unroll
    for (int nn = 0; nn < 4; ++nn) {
        const int n_ = n0 + 16 * nn + q15;
        ob[0 * N_SEQ + n_] = acc[nn][0] + bi.x;
        ob[1 * N_SEQ + n_] = acc[nn][1] + bi.y;
        ob[2 * N_SEQ + n_] = acc[nn][2] + bi.z;
        ob[3 * N_SEQ + n_] = acc[nn][3] + bi.w;
    }
}

extern "C" void kernel_launch(void* const* d_in, const int* in_sizes, int n_in,
                              void* d_out, int out_size, void* d_ws, size_t ws_size,
                              hipStream_t stream) {
    const float* x = (const float*)d_in[0];
    const float* w_qkv = (const float*)d_in[1];
    const float* w_out = (const float*)d_in[2];
    const float* b_out = (const float*)d_in[3];
    ushort* ws16 = (ushort*)d_ws;
    float* k2f = (float*)((char*)d_ws + (12 << 20) + (256 << 10));
    ushort* att16 = (ushort*)((char*)d_ws + (13 << 20));
    ushort* xt16 = (ushort*)((char*)d_ws + (21 << 20));
    ushort* wq16 = (ushort*)((char*)d_ws + (29 << 20));
    ushort* wo16 = (ushort*)((char*)d_ws + (30 << 20));
    float* out = (float*)d_out;

    prep_kernel<<<dim3(1536), 256, 0, stream>>>(x, w_qkv, w_out, xt16, wq16, wo16);
    qkv_mfma<<<dim3(32, 12, 4), 256, 0, stream>>>(xt16, wq16, ws16);
    sq_kernel<<<dim3(256), 256, 0, stream>>>(ws16, k2f);
    attn_kernel<<<dim3(1024), 256, 0, stream>>>(ws16, k2f, att16);
    out_mfma<<<dim3(32, 8, 4), 256, 0, stream>>>(att16, wo16, b_out, out);
}

// Round 19
// 85.617 us; speedup vs baseline: 1.0205x; 1.0205x over previous
//
#include <hip/hip_runtime.h>
#include <math.h>

#define N_SEQ 2048
#define DIMC 512
#define INNER 256
#define C2F (0.17677669529663687f * 1.4426950408889634f)  // scale * log2(e)
#define C2F2 (C2F * C2F)

typedef short bf16x8 __attribute__((ext_vector_type(8)));
typedef float f32x4 __attribute__((ext_vector_type(4)));

// ws layout (bytes):
//  ushort units: Q [0,2M): [bh][g:4][n:2048][8]   K [2M,4M): same
//                Vt [4M,6M): [bh][c:256][d:32][8]
//  k2*C2F2 @12.25MB
//  att16 bf16 @13MB..17MB [b][n][256]
//  xt16 @21MB..29MB   wq16 @29MB..29.75MB   wo16 @30MB..30.25MB

static __device__ __forceinline__ ushort f2bf(float f) {
    uint x = __float_as_uint(f);
    x += 0x7fff + ((x >> 16) & 1);
    return (ushort)(x >> 16);
}
static __device__ __forceinline__ float bf2f(ushort u) {
    return __uint_as_float(((uint)u) << 16);
}
static __device__ __forceinline__ float fast_exp2_neg(float x) {  // exp2(-x)
    float r; asm("v_exp_f32 %0, -%1" : "=v"(r) : "v"(x)); return r;
}
static __device__ __forceinline__ float fast_sqrt(float x) {
    float r; asm("v_sqrt_f32 %0, %1" : "=v"(r) : "v"(x)); return r;
}
// async global->LDS DMA: dest = uniform base + lane*size (HW rule)
static __device__ __forceinline__ void gload16(const void* g, void* l) {
    __builtin_amdgcn_global_load_lds(
        (const __attribute__((address_space(1))) void*)g,
        (__attribute__((address_space(3))) void*)l, 16, 0, 0);
}
static __device__ __forceinline__ void gload4(const void* g, void* l) {
    __builtin_amdgcn_global_load_lds(
        (const __attribute__((address_space(1))) void*)g,
        (__attribute__((address_space(3))) void*)l, 4, 0, 0);
}

// ---------------------------------------------------------------------------
// Fused prep: x transpose/convert (1024 blocks) + weight cvts (512 blocks)
// ---------------------------------------------------------------------------
__global__ void prep_kernel(const float* __restrict__ x,
                            const float* __restrict__ wq,
                            const float* __restrict__ wo,
                            ushort* __restrict__ xt,
                            ushort* __restrict__ wq16,
                            ushort* __restrict__ wo16) {
    __shared__ __align__(16) ushort T[64][72];
    const int bid = blockIdx.x;
    const int t = threadIdx.x;
    if (bid < 1024) {
        const int n0 = (bid & 31) * 64;
        const int c0 = ((bid >> 5) & 7) * 64;
        const int b = bid >> 8;
        const int cl = t >> 4;
        const int n4 = (t & 15) * 4;
        const float* xb = x + ((size_t)b * DIMC + c0) * N_SEQ + n0;
#pragma unroll
        for (int cc = 0; cc < 4; ++cc) {
            const int c = cl + cc * 16;
            float4 v = *(const float4*)(xb + (size_t)c * N_SEQ + n4);
            T[n4 + 0][c] = f2bf(v.x);
            T[n4 + 1][c] = f2bf(v.y);
            T[n4 + 2][c] = f2bf(v.z);
            T[n4 + 3][c] = f2bf(v.w);
        }
        __syncthreads();
        const int nl = t >> 2;
        const int c16 = (t & 3) * 16;
        uint4 v0 = *(const uint4*)&T[nl][c16];
        uint4 v1 = *(const uint4*)&T[nl][c16 + 8];
        ushort* dst = xt + ((size_t)b * N_SEQ + n0 + nl) * DIMC + c0 + c16;
        *(uint4*)dst = v0;
        *(uint4*)(dst + 8) = v1;
    } else if (bid < 1408) {
        int i = ((bid - 1024) * 256 + t) * 4;
        float4 v = *(const float4*)(wq + i);
        ushort4 p;
        p.x = f2bf(v.x); p.y = f2bf(v.y); p.z = f2bf(v.z); p.w = f2bf(v.w);
        *(ushort4*)(wq16 + i) = p;
    } else {
        int i = ((bid - 1408) * 256 + t) * 4;
        float4 v = *(const float4*)(wo + i);
        ushort4 p;
        p.x = f2bf(v.x); p.y = f2bf(v.y); p.z = f2bf(v.z); p.w = f2bf(v.w);
        *(ushort4*)(wo16 + i) = p;
    }
}

// ---------------------------------------------------------------------------
// QKV projection, bf16 MFMA. 64x64 tile, BK=32, 4 waves.
// ---------------------------------------------------------------------------
__global__ __launch_bounds__(256) void qkv_mfma(const ushort* __restrict__ xt,
        const ushort* __restrict__ w16, ushort* __restrict__ ws16) {
    __shared__ __align__(16) ushort Wls[4 * 520];
    __shared__ __align__(16) ushort Xls[4 * 520];
    const int b = blockIdx.z;
    const int o0 = blockIdx.y * 64;
    const int n0 = blockIdx.x * 64;
    const int t = threadIdx.x;
    const int l = t & 63, w = t >> 6;
    const int q15 = l & 15, g = l >> 4;
    f32x4 acc[4];
#pragma unroll
    for (int nn = 0; nn < 4; ++nn) acc[nn] = (f32x4){0.f, 0.f, 0.f, 0.f};
    const int srow = t >> 2, sg = t & 3;
    const ushort* wsrc = w16 + (size_t)(o0 + srow) * DIMC + sg * 8;
    const ushort* xsrc = xt + ((size_t)b * N_SEQ + n0 + srow) * DIMC + sg * 8;
    uint4 wreg = *(const uint4*)wsrc;
    uint4 xreg = *(const uint4*)xsrc;
    for (int k0 = 0; k0 < DIMC; k0 += 32) {
        __builtin_amdgcn_s_barrier();
        __builtin_amdgcn_sched_barrier(0);
        *(uint4*)(Wls + sg * 520 + srow * 8) = wreg;
        *(uint4*)(Xls + sg * 520 + srow * 8) = xreg;
        if (k0 + 32 < DIMC) {
            wreg = *(const uint4*)(wsrc + k0 + 32);
            xreg = *(const uint4*)(xsrc + k0 + 32);
        }
        asm volatile("s_waitcnt lgkmcnt(0)" ::: "memory");
        __builtin_amdgcn_s_barrier();
        __builtin_amdgcn_sched_barrier(0);
        bf16x8 af = *(const bf16x8*)(Wls + g * 520 + (16 * w + q15) * 8);
        __builtin_amdgcn_s_setprio(1);
#pragma unroll
        for (int nn = 0; nn < 4; ++nn) {
            bf16x8 bfr = *(const bf16x8*)(Xls + g * 520 + (16 * nn + q15) * 8);
            acc[nn] = __builtin_amdgcn_mfma_f32_16x16x32_bf16(af, bfr, acc[nn], 0, 0, 0);
        }
        __builtin_amdgcn_s_setprio(0);
    }
    const int oatom = o0 + 16 * w;
    const int t_idx = oatom >> 8;
    const int h = (oatom >> 5) & 7;
    const int bh = b * 8 + h;
    const int d0 = (oatom & 31) + 4 * g;
    if (t_idx < 2) {
        ushort* dst = ws16 + (size_t)t_idx * 2097152 + (size_t)bh * 65536
                      + (size_t)(d0 >> 3) * 16384 + (d0 & 7);
#pragma unroll
        for (int nn = 0; nn < 4; ++nn) {
            const int n_ = n0 + 16 * nn + q15;
            ushort4 p;
            p.x = f2bf(acc[nn][0]); p.y = f2bf(acc[nn][1]);
            p.z = f2bf(acc[nn][2]); p.w = f2bf(acc[nn][3]);
            *(ushort4*)(dst + (size_t)n_ * 8) = p;
        }
    } else {
        ushort* dst = ws16 + (size_t)4194304 + (size_t)bh * 65536;
#pragma unroll
        for (int nn = 0; nn < 4; ++nn) {
            const int n_ = n0 + 16 * nn + q15;
            ushort* dd = dst + (size_t)(n_ >> 3) * 256 + (n_ & 7);
            dd[(d0 + 0) * 8] = f2bf(acc[nn][0]);
            dd[(d0 + 1) * 8] = f2bf(acc[nn][1]);
            dd[(d0 + 2) * 8] = f2bf(acc[nn][2]);
            dd[(d0 + 3) * 8] = f2bf(acc[nn][3]);
        }
    }
}

// ---------------------------------------------------------------------------
// k2 from bf16 values, prescaled by C2F^2
// ---------------------------------------------------------------------------
__global__ void sq_kernel(const ushort* __restrict__ ws16, float* __restrict__ k2) {
    const int idx = blockIdx.x * 256 + threadIdx.x;
    const int bh = idx >> 11, n = idx & 2047;
    const ushort* base = ws16 + 2097152 + (size_t)bh * 65536 + (size_t)n * 8;
    float s = 0.f;
#pragma unroll
    for (int g = 0; g < 4; ++g) {
        uint4 v = *(const uint4*)(base + (size_t)g * 16384);
        uint a[4] = {v.x, v.y, v.z, v.w};
#pragma unroll
        for (int e = 0; e < 4; ++e) {
            float lo = bf2f((ushort)(a[e] & 0xffff));
            float hi = bf2f((ushort)(a[e] >> 16));
            s += lo * lo + hi * hi;
        }
    }
    k2[idx] = s * (float)C2F2;
}

// ---------------------------------------------------------------------------
// Flash L2 attention — 3-buffer LDS ring, ONE barrier per 64-j tile.
// Depth-2 prefetch: STAGE(t+2) is issued after COMPUTE(t); it writes buf
// (t+2)%3 which aliases neither COMPUTE(t)'s buf t%3 nor COMPUTE(t+1)'s
// buf (t+1)%3, and the WAR hazard vs COMPUTE(t) is protected by the barrier
// at iteration t+1 (program order: compute precedes that barrier). vmcnt(3)
// counted in-loop (3 DMAs/wave/tile: K, V, k2-per-tile), drained only at the
// tail. LDS 34.6KB -> 4 blocks/CU, grid 1024 = 4/CU.
// BEST MEASURED CONFIG (R17): total 86.0us, attn 56.0us. The 3.1M LDS bank
// conflicts are measured latency-hidden (R15 removed them; kernel got
// slower). Structural plateau: TLP (R7/R12/R13 null), reg-ILP (R8/R10/R11
// allocator-defeated), LDS-relay (R9 reg.), swizzle (R15 reg.), barrier
// halving (R17 null), cross-tile compute pipeline (R18 null).
// m=0 fixed softmax shift (exact by shift-invariance).
// ---------------------------------------------------------------------------
__global__ __launch_bounds__(256, 4) void attn_kernel(
        const ushort* __restrict__ ws16, const float* __restrict__ k2g,
        ushort* __restrict__ att16) {
    __shared__ __align__(16) ushort Kls[3 * 2048];   // [buf][g:4][j:64][8]
    __shared__ __align__(16) ushort Vls[3 * 2048];   // [buf][c:8][d:32][8]
    __shared__ __align__(16) float k2ls[3 * 64];     // [buf][64]
    __shared__ __align__(16) ushort Pls[4][16][72];  // per-wave P, 144B rows
    const int bid = blockIdx.x;                   // 1024 blocks
    const int sw = (bid & 7) * 128 + (bid >> 3);  // bijective XCD swizzle
    const int q0 = (sw & 31) * 64;
    const int bh = sw >> 5;
    const int b = bh >> 3, h = bh & 7;
    const int tid = threadIdx.x;
    const int l = tid & 63;
    const int w = tid >> 6;
    const int q15 = l & 15;
    const int g = l >> 4;
    const int qrow = q0 + 16 * w + q15;

    const ushort* Qbh = ws16 + (size_t)bh * 65536;
    const ushort* Kbh = ws16 + 2097152 + (size_t)bh * 65536;
    const ushort* Vbh = ws16 + 4194304 + (size_t)bh * 65536;
    const float* k2bh = k2g + (size_t)bh * 2048;

    // stage tile T into ring buffer BUF: wave w owns K g-plane w + V piece w
    // + (redundant-identical across waves) the tile's 64 k2 floats.
#define STAGE(T, BUF)                                                         \
    {                                                                         \
        const int j0s = (T) * 64;                                             \
        gload16(Kbh + (size_t)w * 16384 + (size_t)(j0s + l) * 8,              \
                Kls + (BUF) * 2048 + w * 512);                                \
        gload16(Vbh + (size_t)j0s * 32 + (size_t)w * 512 + (size_t)l * 8,     \
                Vls + (BUF) * 2048 + w * 512);                                \
        gload4(k2bh + j0s + l, k2ls + (BUF) * 64);                            \
    }

    // prologue: depth-2 prefetch
    STAGE(0, 0)
    STAGE(1, 1)

    const bf16x8 qf = *(const bf16x8*)(Qbh + (size_t)g * 16384 + (size_t)qrow * 8);
    float q2l = 0.f;
#pragma unroll
    for (int e = 0; e < 8; ++e) {
        float qe = bf2f((ushort)qf[e]);
        q2l = fmaf(qe, qe, q2l);
    }
    q2l += __shfl_xor(q2l, 16);
    q2l += __shfl_xor(q2l, 32);
    const float q2v = q2l * (float)C2F2;

    ushort* plane = &Pls[w][q15][0];
    f32x4 accO[2];
    accO[0] = (f32x4){0.f, 0.f, 0.f, 0.f};
    accO[1] = (f32x4){0.f, 0.f, 0.f, 0.f};
    float lsm = 0.f;

#define COMPUTE(BC)                                                             \
    {                                                                           \
        const ushort* KlsP = Kls + (BC) * 2048;                                 \
        const ushort* VlsP = Vls + (BC) * 2048;                                 \
        const float* k2P = k2ls + (BC) * 64;                                    \
        bf16x8 kf[4];                                                           \
        _Pragma("unroll")                                                       \
        for (int k = 0; k < 4; ++k)                                             \
            kf[k] = *(const bf16x8*)(KlsP + g * 512 + (16 * k + q15) * 8);      \
        const f32x4 zz = (f32x4){0.f, 0.f, 0.f, 0.f};                           \
        f32x4 st[4];                                                            \
        __builtin_amdgcn_s_setprio(1);                                          \
        _Pragma("unroll")                                                       \
        for (int k = 0; k < 4; ++k)                                             \
            st[k] = __builtin_amdgcn_mfma_f32_16x16x32_bf16(kf[k], qf, zz, 0, 0, 0); \
        __builtin_amdgcn_s_setprio(0);                                          \
        float lt = 0.f;                                                         \
        _Pragma("unroll")                                                       \
        for (int k = 0; k < 4; ++k) {                                           \
            float4 kk = *(const float4*)(k2P + 16 * k + 4 * g);                 \
            float ka[4] = {kk.x, kk.y, kk.z, kk.w};                             \
            float pr[4];                                                        \
            _Pragma("unroll")                                                   \
            for (int r = 0; r < 4; ++r) {                                       \
                float a = q2v + ka[r];                                          \
                float d2 = fmaf(-2.f * (float)C2F2, st[k][r], a);               \
                pr[r] = fast_exp2_neg(fast_sqrt(fmaxf(d2, 1e-12f)));            \
            }                                                                   \
            lt += (pr[0] + pr[1]) + (pr[2] + pr[3]);                            \
            uint pk0, pk1;                                                      \
            asm("v_cvt_pk_bf16_f32 %0, %1, %2" : "=v"(pk0) : "v"(pr[0]), "v"(pr[1])); \
            asm("v_cvt_pk_bf16_f32 %0, %1, %2" : "=v"(pk1) : "v"(pr[2]), "v"(pr[3])); \
            uint2 pv; pv.x = pk0; pv.y = pk1;                                   \
            *(uint2*)(plane + 16 * k + 4 * g) = pv;                             \
        }                                                                       \
        lsm += lt;                                                              \
        __builtin_amdgcn_s_setprio(1);                                          \
        _Pragma("unroll")                                                       \
        for (int jc = 0; jc < 2; ++jc) {                                        \
            bf16x8 pf = *(const bf16x8*)(plane + 32 * jc + 8 * g);              \
            _Pragma("unroll")                                                   \
            for (int dh = 0; dh < 2; ++dh) {                                    \
                bf16x8 vf = *(const bf16x8*)(VlsP + (4 * jc + g) * 256          \
                                             + (16 * dh + q15) * 8);            \
                accO[dh] = __builtin_amdgcn_mfma_f32_16x16x32_bf16(vf, pf, accO[dh], 0, 0, 0); \
            }                                                                   \
        }                                                                       \
        __builtin_amdgcn_s_setprio(0);                                          \
    }

    int bc = 0;           // t % 3
    int sb = 2;           // (t+2) % 3
#pragma unroll 1
    for (int t = 0; t < 31; ++t) {
        asm volatile("s_waitcnt vmcnt(3)" ::: "memory");
        __builtin_amdgcn_s_barrier();
        __builtin_amdgcn_sched_barrier(0);
        COMPUTE(bc)
        if (t + 2 <= 31) {
            STAGE(t + 2, sb)
        }
        bc = (bc == 2) ? 0 : bc + 1;
        sb = (sb == 2) ? 0 : sb + 1;
    }
    asm volatile("s_waitcnt vmcnt(0)" ::: "memory");
    __builtin_amdgcn_s_barrier();
    __builtin_amdgcn_sched_barrier(0);
    COMPUTE(bc)           // t = 31, bc = 31 % 3 = 1
#undef COMPUTE
#undef STAGE

    lsm += __shfl_xor(lsm, 16);
    lsm += __shfl_xor(lsm, 32);
    const float invl = 1.f / lsm;
    ushort* dst = att16 + ((size_t)(b * N_SEQ + qrow)) * INNER + h * 32 + 4 * g;
#pragma unroll
    for (int d = 0; d < 2; ++d) {
        ushort4 o;
        o.x = f2bf(accO[d][0] * invl); o.y = f2bf(accO[d][1] * invl);
        o.z = f2bf(accO[d][2] * invl); o.w = f2bf(accO[d][3] * invl);
        *(ushort4*)(dst + d * 16) = o;
    }
}

// ---------------------------------------------------------------------------
// Output projection, bf16 MFMA
// ---------------------------------------------------------------------------
__global__ __launch_bounds__(256) void out_mfma(const ushort* __restrict__ att16,
        const ushort* __restrict__ wo16, const float* __restrict__ bias,
        float* __restrict__ out) {
    __shared__ __align__(16) ushort Wls[4 * 520];
    __shared__ __align__(16) ushort Als[4 * 520];
    const int b = blockIdx.z;
    const int o0 = blockIdx.y * 64;
    const int n0 = blockIdx.x * 64;
    const int t = threadIdx.x;
    const int l = t & 63, w = t >> 6;
    const int q15 = l & 15, g = l >> 4;
    f32x4 acc[4];
#pragma unroll
    for (int nn = 0; nn < 4; ++nn) acc[nn] = (f32x4){0.f, 0.f, 0.f, 0.f};
    const int srow = t >> 2, sg = t & 3;
    const ushort* wsrc = wo16 + (size_t)(o0 + srow) * INNER + sg * 8;
    const ushort* asrc = att16 + ((size_t)b * N_SEQ + n0 + srow) * INNER + sg * 8;
    uint4 wreg = *(const uint4*)wsrc;
    uint4 areg = *(const uint4*)asrc;
    for (int k0 = 0; k0 < INNER; k0 += 32) {
        __builtin_amdgcn_s_barrier();
        __builtin_amdgcn_sched_barrier(0);
        *(uint4*)(Wls + sg * 520 + srow * 8) = wreg;
        *(uint4*)(Als + sg * 520 + srow * 8) = areg;
        if (k0 + 32 < INNER) {
            wreg = *(const uint4*)(wsrc + k0 + 32);
            areg = *(const uint4*)(asrc + k0 + 32);
        }
        asm volatile("s_waitcnt lgkmcnt(0)" ::: "memory");
        __builtin_amdgcn_s_barrier();
        __builtin_amdgcn_sched_barrier(0);
        bf16x8 af = *(const bf16x8*)(Wls + g * 520 + (16 * w + q15) * 8);
        __builtin_amdgcn_s_setprio(1);
#pragma unroll
        for (int nn = 0; nn < 4; ++nn) {
            bf16x8 bfr = *(const bf16x8*)(Als + g * 520 + (16 * nn + q15) * 8);
            acc[nn] = __builtin_amdgcn_mfma_f32_16x16x32_bf16(af, bfr, acc[nn], 0, 0, 0);
        }
        __builtin_amdgcn_s_setprio(0);
    }
    const int obase = o0 + 16 * w + 4 * g;
    float4 bi = *(const float4*)(bias + obase);
    float* ob = out + ((size_t)b * DIMC + obase) * N_SEQ;
#pragma unroll
    for (int nn = 0; nn < 4; ++nn) {
        const int n_ = n0 + 16 * nn + q15;
        ob[0 * N_SEQ + n_] = acc[nn][0] + bi.x;
        ob[1 * N_SEQ + n_] = acc[nn][1] + bi.y;
        ob[2 * N_SEQ + n_] = acc[nn][2] + bi.z;
        ob[3 * N_SEQ + n_] = acc[nn][3] + bi.w;
    }
}

extern "C" void kernel_launch(void* const* d_in, const int* in_sizes, int n_in,
                              void* d_out, int out_size, void* d_ws, size_t ws_size,
                              hipStream_t stream) {
    const float* x = (const float*)d_in[0];
    const float* w_qkv = (const float*)d_in[1];
    const float* w_out = (const float*)d_in[2];
    const float* b_out = (const float*)d_in[3];
    ushort* ws16 = (ushort*)d_ws;
    float* k2f = (float*)((char*)d_ws + (12 << 20) + (256 << 10));
    ushort* att16 = (ushort*)((char*)d_ws + (13 << 20));
    ushort* xt16 = (ushort*)((char*)d_ws + (21 << 20));
    ushort* wq16 = (ushort*)((char*)d_ws + (29 << 20));
    ushort* wo16 = (ushort*)((char*)d_ws + (30 << 20));
    float* out = (float*)d_out;

    prep_kernel<<<dim3(1536), 256, 0, stream>>>(x, w_qkv, w_out, xt16, wq16, wo16);
    qkv_mfma<<<dim3(32, 12, 4), 256, 0, stream>>>(xt16, wq16, ws16);
    sq_kernel<<<dim3(256), 256, 0, stream>>>(ws16, k2f);
    attn_kernel<<<dim3(1024), 256, 0, stream>>>(ws16, k2f, att16);
    out_mfma<<<dim3(32, 8, 4), 256, 0, stream>>>(att16, wo16, b_out, out);
}